// Round 22
// baseline (107.632 us; speedup 1.0000x reference)
//
#include <hip/hip_runtime.h>
#include <hip/hip_bf16.h>

#define T_TOK 2048
#define H_DIM 768
#define E_NUM 16
#define F_DIM 768
#define TWOF 1536
#define TOPK 4
#define NASSIGN 8192
#define BM 128
#define BK 64
#define KT 12            /* 768/64 k-tiles */
#define NTILE 80         /* padded slots / BM = 10240/128 */
#define NSLOTP (NTILE * BM)
#define MAXT1 10         /* max tiles per expert (count <= 1280) */
#define CHUNK (BM * BK)  /* 8192 halfwords per A/act chunk */
#define WTILE (64 * BK)  /* 4096 halfwords per 64-col weight tile */
#define NRTR 256         /* router blocks: 2048 / 8 */

typedef __bf16 bf16x8 __attribute__((ext_vector_type(8)));
typedef unsigned short us8 __attribute__((ext_vector_type(8)));
typedef float f32x4 __attribute__((ext_vector_type(4)));

__device__ __forceinline__ unsigned short f2bf(float f) {
  unsigned u = __float_as_uint(f);
  u += 0x7FFF + ((u >> 16) & 1);
  return (unsigned short)(u >> 16);
}

__device__ __forceinline__ void gl_lds16(const unsigned short* g, unsigned short* l) {
  __builtin_amdgcn_global_load_lds(
      (const __attribute__((address_space(1))) unsigned int*)g,
      (__attribute__((address_space(3))) unsigned int*)l, 16, 0, 0);
}

// ---------------- 1. router: LDS-free fp64 dot + token-order x->bf16 stream ----------------
__global__ __launch_bounds__(256)
void router_kernel(const float* __restrict__ x, const float* __restrict__ rw,
                   const float* __restrict__ rb, float* __restrict__ scores,
                   int* __restrict__ tk_idx, float* __restrict__ tk_w,
                   int* __restrict__ tmap, float* __restrict__ wgrp,
                   unsigned short* __restrict__ xg) {
  __shared__ float lg[8][16], sc[8][16];
  const int bid = blockIdx.x;
  const int tid = threadIdx.x;
  const int t0 = bid * 8;
  if (tid < 40) {  // 256 blocks x 40 = NSLOTP padded-slot init
    tmap[bid * 40 + tid] = 0;
    wgrp[bid * 40 + tid] = 0.0f;
  }
  { // stream-convert this block's 8 tokens to bf16 (token order, plain layout)
    const int tokr = tid >> 5;          // 0..7
    const int g0 = tid & 31;
    const float* xs = x + (size_t)(t0 + tokr) * H_DIM;
    unsigned short* xd = xg + (size_t)(t0 + tokr) * H_DIM;
    #pragma unroll
    for (int i = 0; i < 3; ++i) {
      const int gg = g0 + i * 32;       // 0..95 (8-halfword granules)
      const f32x4 a = *(const f32x4*)(xs + gg * 8);
      const f32x4 b = *(const f32x4*)(xs + gg * 8 + 4);
      us8 o;
      #pragma unroll
      for (int j = 0; j < 4; ++j) { o[j] = f2bf(a[j]); o[4 + j] = f2bf(b[j]); }
      *(us8*)&xd[gg * 8] = o;
    }
  }
  const int lane32 = tid & 31, tok = tid >> 5;
  const int e = lane32 & 15, q2 = lane32 >> 4;
  const int t = t0 + tok;
  const float* xr = x + (size_t)t * H_DIM + q2 * 384;
  const float* wr = rw + (size_t)e * H_DIM + q2 * 384;
  double a0 = 0, a1 = 0, a2 = 0, a3 = 0;
  #pragma unroll 4
  for (int h = 0; h < 384; h += 4) {
    const f32x4 xv = *(const f32x4*)(xr + h);
    const f32x4 wv = *(const f32x4*)(wr + h);
    a0 += (double)xv[0] * (double)wv[0];
    a1 += (double)xv[1] * (double)wv[1];
    a2 += (double)xv[2] * (double)wv[2];
    a3 += (double)xv[3] * (double)wv[3];
  }
  double acc = (a0 + a1) + (a2 + a3);
  acc += __shfl_xor(acc, 16, 64);   // combine the two h-halves
  if (q2 == 0) lg[tok][e] = (float)acc + rb[e];
  __syncthreads();
  if (lane32 == 0) {
    float v[16];
    #pragma unroll
    for (int i = 0; i < 16; ++i) { v[i] = lg[tok][i]; sc[tok][i] = 0.0f; }
    int idx[TOPK]; float val[TOPK];
    for (int k = 0; k < TOPK; ++k) {
      float best = -3.4e38f; int bi = 0;
      for (int i = 0; i < 16; ++i)
        if (v[i] > best) { best = v[i]; bi = i; }
      idx[k] = bi; val[k] = best; v[bi] = -3.4e38f;
    }
    float s = 0.0f, ev[TOPK];
    for (int k = 0; k < TOPK; ++k) { ev[k] = expf(val[k] - val[0]); s += ev[k]; }
    for (int k = 0; k < TOPK; ++k) {
      float wgt = ev[k] / s;
      sc[tok][idx[k]] = wgt;
      tk_idx[t * TOPK + k] = idx[k];
      tk_w[t * TOPK + k] = wgt;
    }
  }
  __syncthreads();
  if (tid < 128)
    scores[(size_t)(t0 + (tid >> 4)) * 16 + (tid & 15)] = sc[tid >> 4][tid & 15];
}

// ---------------- 2. weight convert + group scan folded into block (0,0,0); hist aliases tg/tu ----------------
__global__ __launch_bounds__(512)
void convert_w_kernel(const float* __restrict__ gup, const float* __restrict__ dwn,
                      unsigned short* __restrict__ gw, unsigned short* __restrict__ uw,
                      unsigned short* __restrict__ dw,
                      const int* __restrict__ tk_idx, const float* __restrict__ tk_w,
                      int* __restrict__ counts, int* __restrict__ offs,
                      int* __restrict__ tmap, float* __restrict__ wgrp) {
  const int ft = blockIdx.x, kt = blockIdx.y, z = blockIdx.z;
  const int tid = threadIdx.x;
  const int n = tid & 63, k8 = tid >> 6;         // k8 = wave index, 0..7
  const int doff = n * BK + 8 * (k8 ^ (n & 7));  // swizzled dest within tile
  __shared__ unsigned short tgu[2 * WTILE];      // 16 KB: tg | tu; aliased by hist in group phase
  __shared__ int seg[16][16];                    // 1 KB
  __shared__ int cnt[16], eoff[16];
  unsigned short* tg = tgu;
  unsigned short* tu = tgu + WTILE;
  if (z < 16) {
    const int e = z;
    const float* src = gup + ((size_t)(e * H_DIM + kt * 64 + k8 * 8)) * TWOF
                           + 2 * (ft * 64 + n);
    us8 g, u;
    #pragma unroll
    for (int j = 0; j < 8; ++j) {
      const float2 p = *(const float2*)(src + (size_t)j * TWOF);
      g[j] = f2bf(p.x); u[j] = f2bf(p.y);
    }
    *(us8*)&tg[doff] = g;
    *(us8*)&tu[doff] = u;
    __syncthreads();
    const size_t tb = (((size_t)e * KT + kt) * 12 + ft) * WTILE;
    *(us8*)&gw[tb + tid * 8] = *(const us8*)&tg[tid * 8];
    *(us8*)&uw[tb + tid * 8] = *(const us8*)&tu[tid * 8];
  } else {
    const int e = z - 16;
    const float* src = dwn + ((size_t)(e * F_DIM + kt * 64 + k8 * 8)) * H_DIM
                           + ft * 64 + n;
    us8 o;
    #pragma unroll
    for (int j = 0; j < 8; ++j) o[j] = f2bf(src[(size_t)j * H_DIM]);
    *(us8*)&tg[doff] = o;
    __syncthreads();
    const size_t tb = (((size_t)e * KT + kt) * 12 + ft) * WTILE;
    *(us8*)&dw[tb + tid * 8] = *(const us8*)&tg[tid * 8];
  }
  // ---- deterministic group-by-expert, appended to the first-dispatched block ----
  if (ft == 0 && kt == 0 && z == 0) {
    int (*hist)[16] = (int(*)[16])tgu;   // 16 KB alias over tg/tu (convert phase done)
    __syncthreads();                     // all convert-phase tg/tu reads complete
    int loc[16];
    int eid[32];
    if (tid < 256) {
      #pragma unroll
      for (int e = 0; e < 16; ++e) loc[e] = 0;
      const int base = tid * 32;
      for (int i = 0; i < 32; ++i) { int e = tk_idx[base + i]; eid[i] = e; loc[e]++; }
      #pragma unroll
      for (int e = 0; e < 16; ++e) hist[tid][e] = loc[e];
    }
    __syncthreads();
    const int s = (tid >> 4) & 15, e16 = tid & 15;
    if (tid < 256) {
      int sum = 0;
      #pragma unroll
      for (int j = 0; j < 16; ++j) sum += hist[s * 16 + j][e16];
      seg[s][e16] = sum;
    }
    __syncthreads();
    if (tid < 16) {
      int run = 0;
      #pragma unroll
      for (int s2 = 0; s2 < 16; ++s2) { int t = seg[s2][tid]; seg[s2][tid] = run; run += t; }
      cnt[tid] = run;
    }
    __syncthreads();
    if (tid < 256) {
      int run = seg[s][e16];
      #pragma unroll
      for (int j = 0; j < 16; ++j) { int t = hist[s * 16 + j][e16]; hist[s * 16 + j][e16] = run; run += t; }
    }
    __syncthreads();
    if (tid == 0) {
      int acc = 0;
      for (int e = 0; e < 16; ++e) { eoff[e] = acc; acc += (cnt[e] + BM - 1) / BM * BM; }
    }
    __syncthreads();
    if (tid < 16) { counts[tid] = cnt[tid]; offs[tid] = eoff[tid]; }
    if (tid < 256) {
      int run[16];
      #pragma unroll
      for (int e = 0; e < 16; ++e) run[e] = hist[tid][e];
      const int base = tid * 32;
      for (int i = 0; i < 32; ++i) {
        int e = eid[i];
        int slot = eoff[e] + run[e]++;
        tmap[slot] = base + i;        // assignment id = t*4 + k
        wgrp[slot] = tk_w[base + i];
      }
    }
  }
}

// ---------------- 3. grouped GEMM1: A gathered from token-order xg (G21 pre-swizzled source) ----------------
__global__ __launch_bounds__(512)
void gemm1_kernel(const unsigned short* __restrict__ xg, const unsigned short* __restrict__ gw,
                  const unsigned short* __restrict__ uw, const float* __restrict__ gupb,
                  const int* __restrict__ counts, const int* __restrict__ offs,
                  const int* __restrict__ tmap, unsigned short* __restrict__ act) {
  // 960 blocks = 8 XCDs x 120; bijective
  const int bid = blockIdx.x;
  const int swz = (bid & 7) * 120 + (bid >> 3);
  const int ey = swz / 6, ft = swz % 6;
  const int e = ey / MAXT1, tile = ey % MAXT1;
  const int count = counts[e];
  if (tile * BM >= count) return;
  const int tileg = (offs[e] >> 7) + tile;
  const int tid = threadIdx.x;
  const int wv = tid >> 6, lane = tid & 63;
  const int ml = lane & 15, lh = lane >> 4;
  const int wm = wv >> 2, wn = wv & 3;

  __shared__ unsigned short lA[CHUNK];    // 16KB A tile [128][64], LDS-linear
  __shared__ unsigned short lBg[CHUNK];   // 16KB gate: 2 adjacent 64-col WTILEs
  __shared__ unsigned short lBu[CHUNK];   // 16KB up

  const int arow = tid >> 3;
  const int agr = (tid & 7) ^ (arow & 7);   // (arow+64)&7 == arow&7
  const int t0 = tmap[tileg * BM + arow] >> 2;
  const int t1 = tmap[tileg * BM + 64 + arow] >> 2;
  const unsigned short* a0 = xg + (size_t)t0 * H_DIM + agr * 8;
  const unsigned short* a1 = xg + (size_t)t1 * H_DIM + agr * 8;

  const unsigned short* gb = gw + ((size_t)e * KT * 12 + ft * 2) * WTILE;
  const unsigned short* ub = uw + ((size_t)e * KT * 12 + ft * 2) * WTILE;

  f32x4 accg[4][2] = {};
  f32x4 accu[4][2] = {};

  for (int kt = 0; kt < KT; ++kt) {
    const unsigned short* gs = gb + (size_t)kt * 12 * WTILE;
    const unsigned short* us = ub + (size_t)kt * 12 * WTILE;
    gl_lds16(a0 + kt * 64, &lA[tid * 8]);
    gl_lds16(a1 + kt * 64, &lA[(512 + tid) * 8]);
    gl_lds16(gs + tid * 8, &lBg[tid * 8]);
    gl_lds16(gs + (512 + tid) * 8, &lBg[(512 + tid) * 8]);
    gl_lds16(us + tid * 8, &lBu[tid * 8]);
    gl_lds16(us + (512 + tid) * 8, &lBu[(512 + tid) * 8]);
    __syncthreads();
    #pragma unroll
    for (int ks = 0; ks < 2; ++ks) {
      const int slot = ks * 4 + lh;
      bf16x8 af[4];
      #pragma unroll
      for (int mf = 0; mf < 4; ++mf) {
        const int ar = wm * 64 + mf * 16 + ml;
        af[mf] = __builtin_bit_cast(bf16x8, *(const us8*)&lA[ar * BK + 8 * (slot ^ (ar & 7))]);
      }
      #pragma unroll
      for (int nf = 0; nf < 2; ++nf) {
        const int br = wn * 32 + nf * 16 + ml;      // 0..127
        const int ba = (br >> 6) * WTILE + (br & 63) * BK + 8 * (slot ^ (br & 7));
        bf16x8 bg = __builtin_bit_cast(bf16x8, *(const us8*)&lBg[ba]);
        bf16x8 bu = __builtin_bit_cast(bf16x8, *(const us8*)&lBu[ba]);
        #pragma unroll
        for (int mf = 0; mf < 4; ++mf) {
          accg[mf][nf] = __builtin_amdgcn_mfma_f32_16x16x32_bf16(af[mf], bg, accg[mf][nf], 0, 0, 0);
          accu[mf][nf] = __builtin_amdgcn_mfma_f32_16x16x32_bf16(af[mf], bu, accu[mf][nf], 0, 0, 0);
        }
      }
    }
    __syncthreads();
  }
  // epilogue: activation; chunk0 (cols 0..63) -> lA, chunk1 (cols 64..127) -> lBg
  unsigned short* tbuf = (wn & 2) ? lBg : lA;
  #pragma unroll
  for (int mf = 0; mf < 4; ++mf) {
    #pragma unroll
    for (int nf = 0; nf < 2; ++nf) {
      const int fcl = wn * 32 + nf * 16 + ml;       // 0..127
      const int c = fcl & 63;
      const int fc = ft * 128 + fcl;
      const float bgv = gupb[(size_t)e * TWOF + 2 * fc];
      const float buv = gupb[(size_t)e * TWOF + 2 * fc + 1];
      #pragma unroll
      for (int r = 0; r < 4; ++r) {
        const int m = wm * 64 + mf * 16 + lh * 4 + r;
        float g = accg[mf][nf][r] + bgv;
        float u = accu[mf][nf][r] + buv;
        g = fminf(g, 7.0f);
        u = fminf(fmaxf(u, -7.0f), 7.0f);
        const float glu = g / (1.0f + __expf(-1.702f * g));
        tbuf[m * BK + 8 * ((c >> 3) ^ (m & 7)) + (c & 7)] = f2bf((u + 1.0f) * glu);
      }
    }
  }
  __syncthreads();
  unsigned short* ob0 = act + ((size_t)tileg * KT + ft * 2) * CHUNK;
  unsigned short* ob1 = ob0 + CHUNK;
  #pragma unroll
  for (int i = 0; i < 2; ++i) {
    *(us8*)&ob0[(i * 512 + tid) * 8] = *(const us8*)&lA[(i * 512 + tid) * 8];
    *(us8*)&ob1[(i * 512 + tid) * 8] = *(const us8*)&lBg[(i * 512 + tid) * 8];
  }
}

// ---------------- 4. grouped GEMM2: 128m x 128h, 512 thr, XCD-swizzled, bf16 partial ----------------
__global__ __launch_bounds__(512)
void gemm2_kernel(const unsigned short* __restrict__ act, const unsigned short* __restrict__ dw,
                  const float* __restrict__ dwnb, const int* __restrict__ counts,
                  const int* __restrict__ offs, const int* __restrict__ tmap,
                  const float* __restrict__ wgrp, unsigned short* __restrict__ partial) {
  const int bid = blockIdx.x;
  const int swz = (bid & 7) * 120 + (bid >> 3);
  const int ey = swz / 6, ft = swz % 6;
  const int e = ey / MAXT1, tile = ey % MAXT1;
  const int count = counts[e];
  if (tile * BM >= count) return;
  const int off = offs[e];
  const int tileg = (off >> 7) + tile;
  const int tid = threadIdx.x;
  const int wv = tid >> 6, lane = tid & 63;
  const int ml = lane & 15, lh = lane >> 4;
  const int wm = wv >> 2, wn = wv & 3;

  __shared__ unsigned short lA[CHUNK];   // 16KB
  __shared__ unsigned short lB[CHUNK];   // 16KB: 2 adjacent 64-col WTILEs

  const unsigned short* ab = act + (size_t)tileg * KT * CHUNK;
  const unsigned short* bb = dw + ((size_t)e * KT * 12 + ft * 2) * WTILE;

  f32x4 acc[4][2] = {};

  for (int kt = 0; kt < KT; ++kt) {
    const unsigned short* as = ab + kt * CHUNK;
    const unsigned short* bs = bb + (size_t)kt * 12 * WTILE;
    gl_lds16(as + tid * 8, &lA[tid * 8]);
    gl_lds16(as + (512 + tid) * 8, &lA[(512 + tid) * 8]);
    gl_lds16(bs + tid * 8, &lB[tid * 8]);
    gl_lds16(bs + (512 + tid) * 8, &lB[(512 + tid) * 8]);
    __syncthreads();
    #pragma unroll
    for (int ks = 0; ks < 2; ++ks) {
      const int slot = ks * 4 + lh;
      bf16x8 af[4];
      #pragma unroll
      for (int mf = 0; mf < 4; ++mf) {
        const int ar = wm * 64 + mf * 16 + ml;
        af[mf] = __builtin_bit_cast(bf16x8, *(const us8*)&lA[ar * BK + 8 * (slot ^ (ar & 7))]);
      }
      #pragma unroll
      for (int nf = 0; nf < 2; ++nf) {
        const int br = wn * 32 + nf * 16 + ml;
        const int ba = (br >> 6) * WTILE + (br & 63) * BK + 8 * (slot ^ (br & 7));
        bf16x8 bv = __builtin_bit_cast(bf16x8, *(const us8*)&lB[ba]);
        #pragma unroll
        for (int mf = 0; mf < 4; ++mf)
          acc[mf][nf] = __builtin_amdgcn_mfma_f32_16x16x32_bf16(af[mf], bv, acc[mf][nf], 0, 0, 0);
      }
    }
    __syncthreads();
  }
  #pragma unroll
  for (int mf = 0; mf < 4; ++mf) {
    #pragma unroll
    for (int nf = 0; nf < 2; ++nf) {
      const int hc = ft * 128 + wn * 32 + nf * 16 + ml;
      const float bias = dwnb[(size_t)e * H_DIM + hc];
      #pragma unroll
      for (int r = 0; r < 4; ++r) {
        const int m = tile * BM + wm * 64 + mf * 16 + lh * 4 + r;
        if (m < count) {
          const int slot = off + m;
          partial[(size_t)tmap[slot] * H_DIM + hc] =
              f2bf(wgrp[slot] * (acc[mf][nf][r] + bias));
        }
      }
    }
  }
}

// ---------------- 5. reduce bf16 partials over k ----------------
__global__ __launch_bounds__(256)
void reduce_kernel(const unsigned short* __restrict__ partial, float* __restrict__ out) {
  const int idx = blockIdx.x * 256 + threadIdx.x;   // T_TOK * 96 total
  const int t = idx / 96, g = idx - (idx / 96) * 96;
  const int h0 = g * 8;
  float s[8] = {0, 0, 0, 0, 0, 0, 0, 0};
  #pragma unroll
  for (int k = 0; k < 4; ++k) {
    const us8 p = *(const us8*)&partial[(size_t)(t * 4 + k) * H_DIM + h0];
    #pragma unroll
    for (int j = 0; j < 8; ++j)
      s[j] += __uint_as_float((unsigned)p[j] << 16);
  }
  f32x4 o0 = {s[0], s[1], s[2], s[3]};
  f32x4 o1 = {s[4], s[5], s[6], s[7]};
  *(f32x4*)&out[(size_t)t * H_DIM + h0] = o0;
  *(f32x4*)&out[(size_t)t * H_DIM + h0 + 4] = o1;
}

extern "C" void kernel_launch(void* const* d_in, const int* in_sizes, int n_in,
                              void* d_out, int out_size, void* d_ws, size_t ws_size,
                              hipStream_t stream) {
  const float* x    = (const float*)d_in[0];
  const float* rw   = (const float*)d_in[1];
  const float* rb   = (const float*)d_in[2];
  const float* gup  = (const float*)d_in[3];
  const float* gupb = (const float*)d_in[4];
  const float* dwn  = (const float*)d_in[5];
  const float* dwnb = (const float*)d_in[6];
  float* out = (float*)d_out;
  float* scores = out + (size_t)T_TOK * H_DIM;

  char* w = (char*)d_ws;
  int*   tk_idx = (int*)w;            w += NASSIGN * 4;
  float* tk_w   = (float*)w;          w += NASSIGN * 4;
  int*   counts = (int*)w;            w += 64;
  int*   offs   = (int*)w;            w += 64;
  int*   tmap   = (int*)w;            w += NSLOTP * 4;
  float* wgrp   = (float*)w;          w += NSLOTP * 4;
  unsigned short* gw = (unsigned short*)w; w += (size_t)E_NUM * KT * 12 * WTILE * 2;
  unsigned short* uw = (unsigned short*)w; w += (size_t)E_NUM * KT * 12 * WTILE * 2;
  unsigned short* dw = (unsigned short*)w; w += (size_t)E_NUM * KT * 12 * WTILE * 2;
  unsigned short* xg = (unsigned short*)w; w += (size_t)T_TOK * H_DIM * 2;
  unsigned short* act = (unsigned short*)w; w += (size_t)NTILE * KT * CHUNK * 2;
  unsigned short* partial = (unsigned short*)w; w += (size_t)NASSIGN * H_DIM * 2;

  router_kernel<<<NRTR, 256, 0, stream>>>(x, rw, rb, scores, tk_idx, tk_w, tmap, wgrp, xg);
  convert_w_kernel<<<dim3(12, 12, 32), 512, 0, stream>>>(
      gup, dwn, gw, uw, dw, tk_idx, tk_w, counts, offs, tmap, wgrp);
  gemm1_kernel<<<6 * E_NUM * MAXT1, 512, 0, stream>>>(
      xg, gw, uw, gupb, counts, offs, tmap, act);
  gemm2_kernel<<<6 * E_NUM * MAXT1, 512, 0, stream>>>(
      act, dw, dwnb, counts, offs, tmap, wgrp, partial);
  reduce_kernel<<<(T_TOK * 96) / 256, 256, 0, stream>>>(partial, out);
}

// Round 23
// 106.091 us; speedup vs baseline: 1.0145x; 1.0145x over previous
//
#include <hip/hip_runtime.h>
#include <hip/hip_bf16.h>

#define T_TOK 2048
#define H_DIM 768
#define E_NUM 16
#define F_DIM 768
#define TWOF 1536
#define TOPK 4
#define NASSIGN 8192
#define BM 128
#define BK 64
#define KT 12            /* 768/64 k-tiles */
#define NTILE 80         /* padded slots / BM = 10240/128 */
#define NSLOTP (NTILE * BM)
#define MAXT1 10         /* max tiles per expert (count <= 1280) */
#define CHUNK (BM * BK)  /* 8192 halfwords per A/act chunk */
#define WTILE (64 * BK)  /* 4096 halfwords per 64-col weight tile */
#define NRTR 256         /* router blocks: 2048 / 8 */

typedef __bf16 bf16x8 __attribute__((ext_vector_type(8)));
typedef unsigned short us8 __attribute__((ext_vector_type(8)));
typedef float f32x4 __attribute__((ext_vector_type(4)));

__device__ __forceinline__ unsigned short f2bf(float f) {
  unsigned u = __float_as_uint(f);
  u += 0x7FFF + ((u >> 16) & 1);
  return (unsigned short)(u >> 16);
}

__device__ __forceinline__ void gl_lds16(const unsigned short* g, unsigned short* l) {
  __builtin_amdgcn_global_load_lds(
      (const __attribute__((address_space(1))) unsigned int*)g,
      (__attribute__((address_space(3))) unsigned int*)l, 16, 0, 0);
}

// ---------------- 1. router: LDS-free fp64 dot + token-order x->bf16 stream ----------------
__global__ __launch_bounds__(256)
void router_kernel(const float* __restrict__ x, const float* __restrict__ rw,
                   const float* __restrict__ rb, float* __restrict__ scores,
                   int* __restrict__ tk_idx, float* __restrict__ tk_w,
                   int* __restrict__ tmap, float* __restrict__ wgrp,
                   unsigned short* __restrict__ xg) {
  __shared__ float lg[8][16], sc[8][16];
  const int bid = blockIdx.x;
  const int tid = threadIdx.x;
  const int t0 = bid * 8;
  if (tid < 40) {  // 256 blocks x 40 = NSLOTP padded-slot init
    tmap[bid * 40 + tid] = 0;
    wgrp[bid * 40 + tid] = 0.0f;
  }
  { // stream-convert this block's 8 tokens to bf16 (token order, plain layout)
    const int tokr = tid >> 5;          // 0..7
    const int g0 = tid & 31;
    const float* xs = x + (size_t)(t0 + tokr) * H_DIM;
    unsigned short* xd = xg + (size_t)(t0 + tokr) * H_DIM;
    #pragma unroll
    for (int i = 0; i < 3; ++i) {
      const int gg = g0 + i * 32;       // 0..95 (8-halfword granules)
      const f32x4 a = *(const f32x4*)(xs + gg * 8);
      const f32x4 b = *(const f32x4*)(xs + gg * 8 + 4);
      us8 o;
      #pragma unroll
      for (int j = 0; j < 4; ++j) { o[j] = f2bf(a[j]); o[4 + j] = f2bf(b[j]); }
      *(us8*)&xd[gg * 8] = o;
    }
  }
  const int lane32 = tid & 31, tok = tid >> 5;
  const int e = lane32 & 15, q2 = lane32 >> 4;
  const int t = t0 + tok;
  const float* xr = x + (size_t)t * H_DIM + q2 * 384;
  const float* wr = rw + (size_t)e * H_DIM + q2 * 384;
  double a0 = 0, a1 = 0, a2 = 0, a3 = 0;
  #pragma unroll 4
  for (int h = 0; h < 384; h += 4) {
    const f32x4 xv = *(const f32x4*)(xr + h);
    const f32x4 wv = *(const f32x4*)(wr + h);
    a0 += (double)xv[0] * (double)wv[0];
    a1 += (double)xv[1] * (double)wv[1];
    a2 += (double)xv[2] * (double)wv[2];
    a3 += (double)xv[3] * (double)wv[3];
  }
  double acc = (a0 + a1) + (a2 + a3);
  acc += __shfl_xor(acc, 16, 64);   // combine the two h-halves
  if (q2 == 0) lg[tok][e] = (float)acc + rb[e];
  __syncthreads();
  if (lane32 == 0) {
    float v[16];
    #pragma unroll
    for (int i = 0; i < 16; ++i) { v[i] = lg[tok][i]; sc[tok][i] = 0.0f; }
    int idx[TOPK]; float val[TOPK];
    for (int k = 0; k < TOPK; ++k) {
      float best = -3.4e38f; int bi = 0;
      for (int i = 0; i < 16; ++i)
        if (v[i] > best) { best = v[i]; bi = i; }
      idx[k] = bi; val[k] = best; v[bi] = -3.4e38f;
    }
    float s = 0.0f, ev[TOPK];
    for (int k = 0; k < TOPK; ++k) { ev[k] = expf(val[k] - val[0]); s += ev[k]; }
    for (int k = 0; k < TOPK; ++k) {
      float wgt = ev[k] / s;
      sc[tok][idx[k]] = wgt;
      tk_idx[t * TOPK + k] = idx[k];
      tk_w[t * TOPK + k] = wgt;
    }
  }
  __syncthreads();
  if (tid < 128)
    scores[(size_t)(t0 + (tid >> 4)) * 16 + (tid & 15)] = sc[tid >> 4][tid & 15];
}

// ---------------- 2. weight convert v6: contiguous reads + k-octet-major contiguous writes ----------------
// tile layout: element (n, k) at k8*512 + ((n ^ (k8&7))<<3) + (k&7). Block = (e*12+kt, r8, z).
// group scan folded into block (0,0,0); hist aliases buf.
__global__ __launch_bounds__(512)
void convert_w_kernel(const float* __restrict__ gup, const float* __restrict__ dwn,
                      unsigned short* __restrict__ gw, unsigned short* __restrict__ uw,
                      unsigned short* __restrict__ dw,
                      const int* __restrict__ tk_idx, const float* __restrict__ tk_w,
                      int* __restrict__ counts, int* __restrict__ offs,
                      int* __restrict__ tmap, float* __restrict__ wgrp) {
  const int xe = blockIdx.x;            // 0..191: e*12+kt
  const int e = xe / 12, kt = xe % 12;
  const int r8 = blockIdx.y;            // 0..7: k-octet
  const int z = blockIdx.z;             // 0: gate_up, 1: down
  const int tid = threadIdx.x;
  __shared__ unsigned short buf[12288]; // 24.6 KB; [row][f] bf16 staging; hist alias in group phase
  __shared__ int seg[16][16];
  __shared__ int cnt[16], eoff[16];
  if (z == 0) {
    unsigned short* lg = buf;           // gate [8][768]
    unsigned short* lu = buf + 6144;    // up   [8][768]
    const float* src = gup + ((size_t)(e * H_DIM + kt * 64 + r8 * 8)) * TWOF;
    #pragma unroll
    for (int i = 0; i < 6; ++i) {
      const int q = i * 512 + tid;      // f32x4 index, 0..3071 (contiguous 48KB stream)
      const f32x4 v = *(const f32x4*)(src + 4 * q);
      const int row = q / 384;
      const int fp = (q - row * 384) * 2;   // f-col of first pair
      const int a = row * 768 + fp;
      *(unsigned*)&lg[a] = (unsigned)f2bf(v[0]) | ((unsigned)f2bf(v[2]) << 16);
      *(unsigned*)&lu[a] = (unsigned)f2bf(v[1]) | ((unsigned)f2bf(v[3]) << 16);
    }
    __syncthreads();
    #pragma unroll
    for (int i = 0; i < 3; ++i) {
      const int o = i * 512 + tid;      // 0..1535: which*768 + ft*64 + n
      const int which = o / 768;
      const int rem = o - which * 768;
      const int ft = rem >> 6, n = rem & 63;
      const unsigned short* ls = which ? lu : lg;
      us8 v;
      #pragma unroll
      for (int j = 0; j < 8; ++j) v[j] = ls[j * 768 + rem];
      unsigned short* dst = (which ? uw : gw)
          + (((size_t)e * KT + kt) * 12 + ft) * WTILE + r8 * 512 + ((n ^ (r8 & 7)) << 3);
      *(us8*)dst = v;
    }
  } else {
    unsigned short* lv = buf;           // [8][768]
    const float* src = dwn + ((size_t)(e * F_DIM + kt * 64 + r8 * 8)) * H_DIM;
    #pragma unroll
    for (int i = 0; i < 3; ++i) {
      const int q = i * 512 + tid;      // 0..1535 (contiguous 24KB stream)
      const f32x4 v = *(const f32x4*)(src + 4 * q);
      const int row = q / 192;
      const int c = (q - row * 192) * 4;
      const int a = row * 768 + c;
      *(unsigned*)&lv[a]     = (unsigned)f2bf(v[0]) | ((unsigned)f2bf(v[1]) << 16);
      *(unsigned*)&lv[a + 2] = (unsigned)f2bf(v[2]) | ((unsigned)f2bf(v[3]) << 16);
    }
    __syncthreads();
    for (int o = tid; o < 768; o += 512) {
      const int ft = o >> 6, n = o & 63;
      us8 v;
      #pragma unroll
      for (int j = 0; j < 8; ++j) v[j] = lv[j * 768 + o];
      unsigned short* dst = dw
          + (((size_t)e * KT + kt) * 12 + ft) * WTILE + r8 * 512 + ((n ^ (r8 & 7)) << 3);
      *(us8*)dst = v;
    }
  }
  // ---- deterministic group-by-expert, appended to block (0,0,0) ----
  if (xe == 0 && r8 == 0 && z == 0) {
    int (*hist)[16] = (int(*)[16])buf;   // 16 KB alias (convert phase done with buf)
    __syncthreads();
    int loc[16];
    int eid[32];
    if (tid < 256) {
      #pragma unroll
      for (int e2 = 0; e2 < 16; ++e2) loc[e2] = 0;
      const int base = tid * 32;
      for (int i = 0; i < 32; ++i) { int e2 = tk_idx[base + i]; eid[i] = e2; loc[e2]++; }
      #pragma unroll
      for (int e2 = 0; e2 < 16; ++e2) hist[tid][e2] = loc[e2];
    }
    __syncthreads();
    const int s = (tid >> 4) & 15, e16 = tid & 15;
    if (tid < 256) {
      int sum = 0;
      #pragma unroll
      for (int j = 0; j < 16; ++j) sum += hist[s * 16 + j][e16];
      seg[s][e16] = sum;
    }
    __syncthreads();
    if (tid < 16) {
      int run = 0;
      #pragma unroll
      for (int s2 = 0; s2 < 16; ++s2) { int t = seg[s2][tid]; seg[s2][tid] = run; run += t; }
      cnt[tid] = run;
    }
    __syncthreads();
    if (tid < 256) {
      int run = seg[s][e16];
      #pragma unroll
      for (int j = 0; j < 16; ++j) { int t = hist[s * 16 + j][e16]; hist[s * 16 + j][e16] = run; run += t; }
    }
    __syncthreads();
    if (tid == 0) {
      int acc = 0;
      for (int e2 = 0; e2 < 16; ++e2) { eoff[e2] = acc; acc += (cnt[e2] + BM - 1) / BM * BM; }
    }
    __syncthreads();
    if (tid < 16) { counts[tid] = cnt[tid]; offs[tid] = eoff[tid]; }
    if (tid < 256) {
      int run[16];
      #pragma unroll
      for (int e2 = 0; e2 < 16; ++e2) run[e2] = hist[tid][e2];
      const int base = tid * 32;
      for (int i = 0; i < 32; ++i) {
        int e2 = eid[i];
        int slot = eoff[e2] + run[e2]++;
        tmap[slot] = base + i;        // assignment id = t*4 + k
        wgrp[slot] = tk_w[base + i];
      }
    }
  }
}

// ---------------- 3. grouped GEMM1: A from token-order xg; B in k-octet-major tiles ----------------
__global__ __launch_bounds__(512)
void gemm1_kernel(const unsigned short* __restrict__ xg, const unsigned short* __restrict__ gw,
                  const unsigned short* __restrict__ uw, const float* __restrict__ gupb,
                  const int* __restrict__ counts, const int* __restrict__ offs,
                  const int* __restrict__ tmap, unsigned short* __restrict__ act) {
  // 960 blocks = 8 XCDs x 120; bijective
  const int bid = blockIdx.x;
  const int swz = (bid & 7) * 120 + (bid >> 3);
  const int ey = swz / 6, ft = swz % 6;
  const int e = ey / MAXT1, tile = ey % MAXT1;
  const int count = counts[e];
  if (tile * BM >= count) return;
  const int tileg = (offs[e] >> 7) + tile;
  const int tid = threadIdx.x;
  const int wv = tid >> 6, lane = tid & 63;
  const int ml = lane & 15, lh = lane >> 4;
  const int wm = wv >> 2, wn = wv & 3;

  __shared__ unsigned short lA[CHUNK];    // 16KB A tile [128][64], LDS-linear
  __shared__ unsigned short lBg[CHUNK];   // 16KB gate: 2 adjacent 64-col tiles (k8-major)
  __shared__ unsigned short lBu[CHUNK];   // 16KB up

  const int arow = tid >> 3;
  const int agr = (tid & 7) ^ (arow & 7);   // (arow+64)&7 == arow&7
  const int t0 = tmap[tileg * BM + arow] >> 2;
  const int t1 = tmap[tileg * BM + 64 + arow] >> 2;
  const unsigned short* a0 = xg + (size_t)t0 * H_DIM + agr * 8;
  const unsigned short* a1 = xg + (size_t)t1 * H_DIM + agr * 8;

  const unsigned short* gb = gw + ((size_t)e * KT * 12 + ft * 2) * WTILE;
  const unsigned short* ub = uw + ((size_t)e * KT * 12 + ft * 2) * WTILE;

  f32x4 accg[4][2] = {};
  f32x4 accu[4][2] = {};

  for (int kt = 0; kt < KT; ++kt) {
    const unsigned short* gs = gb + (size_t)kt * 12 * WTILE;
    const unsigned short* us = ub + (size_t)kt * 12 * WTILE;
    gl_lds16(a0 + kt * 64, &lA[tid * 8]);
    gl_lds16(a1 + kt * 64, &lA[(512 + tid) * 8]);
    gl_lds16(gs + tid * 8, &lBg[tid * 8]);
    gl_lds16(gs + (512 + tid) * 8, &lBg[(512 + tid) * 8]);
    gl_lds16(us + tid * 8, &lBu[tid * 8]);
    gl_lds16(us + (512 + tid) * 8, &lBu[(512 + tid) * 8]);
    __syncthreads();
    #pragma unroll
    for (int ks = 0; ks < 2; ++ks) {
      const int slot = ks * 4 + lh;
      bf16x8 af[4];
      #pragma unroll
      for (int mf = 0; mf < 4; ++mf) {
        const int ar = wm * 64 + mf * 16 + ml;
        af[mf] = __builtin_bit_cast(bf16x8, *(const us8*)&lA[ar * BK + 8 * (slot ^ (ar & 7))]);
      }
      #pragma unroll
      for (int nf = 0; nf < 2; ++nf) {
        const int br = wn * 32 + nf * 16 + ml;      // 0..127
        const int ba = (br >> 6) * WTILE + slot * 512 + (((br & 63) ^ (slot & 7)) << 3);
        bf16x8 bg = __builtin_bit_cast(bf16x8, *(const us8*)&lBg[ba]);
        bf16x8 bu = __builtin_bit_cast(bf16x8, *(const us8*)&lBu[ba]);
        #pragma unroll
        for (int mf = 0; mf < 4; ++mf) {
          accg[mf][nf] = __builtin_amdgcn_mfma_f32_16x16x32_bf16(af[mf], bg, accg[mf][nf], 0, 0, 0);
          accu[mf][nf] = __builtin_amdgcn_mfma_f32_16x16x32_bf16(af[mf], bu, accu[mf][nf], 0, 0, 0);
        }
      }
    }
    __syncthreads();
  }
  // epilogue: activation; chunk0 (cols 0..63) -> lA, chunk1 (cols 64..127) -> lBg (OLD act layout)
  unsigned short* tbuf = (wn & 2) ? lBg : lA;
  #pragma unroll
  for (int mf = 0; mf < 4; ++mf) {
    #pragma unroll
    for (int nf = 0; nf < 2; ++nf) {
      const int fcl = wn * 32 + nf * 16 + ml;       // 0..127
      const int c = fcl & 63;
      const int fc = ft * 128 + fcl;
      const float bgv = gupb[(size_t)e * TWOF + 2 * fc];
      const float buv = gupb[(size_t)e * TWOF + 2 * fc + 1];
      #pragma unroll
      for (int r = 0; r < 4; ++r) {
        const int m = wm * 64 + mf * 16 + lh * 4 + r;
        float g = accg[mf][nf][r] + bgv;
        float u = accu[mf][nf][r] + buv;
        g = fminf(g, 7.0f);
        u = fminf(fmaxf(u, -7.0f), 7.0f);
        const float glu = g / (1.0f + __expf(-1.702f * g));
        tbuf[m * BK + 8 * ((c >> 3) ^ (m & 7)) + (c & 7)] = f2bf((u + 1.0f) * glu);
      }
    }
  }
  __syncthreads();
  unsigned short* ob0 = act + ((size_t)tileg * KT + ft * 2) * CHUNK;
  unsigned short* ob1 = ob0 + CHUNK;
  #pragma unroll
  for (int i = 0; i < 2; ++i) {
    *(us8*)&ob0[(i * 512 + tid) * 8] = *(const us8*)&lA[(i * 512 + tid) * 8];
    *(us8*)&ob1[(i * 512 + tid) * 8] = *(const us8*)&lBg[(i * 512 + tid) * 8];
  }
}

// ---------------- 4. grouped GEMM2: A = act (old layout), B = dw (k8-major), bf16 partial ----------------
__global__ __launch_bounds__(512)
void gemm2_kernel(const unsigned short* __restrict__ act, const unsigned short* __restrict__ dw,
                  const float* __restrict__ dwnb, const int* __restrict__ counts,
                  const int* __restrict__ offs, const int* __restrict__ tmap,
                  const float* __restrict__ wgrp, unsigned short* __restrict__ partial) {
  const int bid = blockIdx.x;
  const int swz = (bid & 7) * 120 + (bid >> 3);
  const int ey = swz / 6, ft = swz % 6;
  const int e = ey / MAXT1, tile = ey % MAXT1;
  const int count = counts[e];
  if (tile * BM >= count) return;
  const int off = offs[e];
  const int tileg = (off >> 7) + tile;
  const int tid = threadIdx.x;
  const int wv = tid >> 6, lane = tid & 63;
  const int ml = lane & 15, lh = lane >> 4;
  const int wm = wv >> 2, wn = wv & 3;

  __shared__ unsigned short lA[CHUNK];   // 16KB
  __shared__ unsigned short lB[CHUNK];   // 16KB: 2 adjacent 64-col tiles (k8-major)

  const unsigned short* ab = act + (size_t)tileg * KT * CHUNK;
  const unsigned short* bb = dw + ((size_t)e * KT * 12 + ft * 2) * WTILE;

  f32x4 acc[4][2] = {};

  for (int kt = 0; kt < KT; ++kt) {
    const unsigned short* as = ab + kt * CHUNK;
    const unsigned short* bs = bb + (size_t)kt * 12 * WTILE;
    gl_lds16(as + tid * 8, &lA[tid * 8]);
    gl_lds16(as + (512 + tid) * 8, &lA[(512 + tid) * 8]);
    gl_lds16(bs + tid * 8, &lB[tid * 8]);
    gl_lds16(bs + (512 + tid) * 8, &lB[(512 + tid) * 8]);
    __syncthreads();
    #pragma unroll
    for (int ks = 0; ks < 2; ++ks) {
      const int slot = ks * 4 + lh;
      bf16x8 af[4];
      #pragma unroll
      for (int mf = 0; mf < 4; ++mf) {
        const int ar = wm * 64 + mf * 16 + ml;
        af[mf] = __builtin_bit_cast(bf16x8, *(const us8*)&lA[ar * BK + 8 * (slot ^ (ar & 7))]);
      }
      #pragma unroll
      for (int nf = 0; nf < 2; ++nf) {
        const int br = wn * 32 + nf * 16 + ml;
        const int ba = (br >> 6) * WTILE + slot * 512 + (((br & 63) ^ (slot & 7)) << 3);
        bf16x8 bv = __builtin_bit_cast(bf16x8, *(const us8*)&lB[ba]);
        #pragma unroll
        for (int mf = 0; mf < 4; ++mf)
          acc[mf][nf] = __builtin_amdgcn_mfma_f32_16x16x32_bf16(af[mf], bv, acc[mf][nf], 0, 0, 0);
      }
    }
    __syncthreads();
  }
  #pragma unroll
  for (int mf = 0; mf < 4; ++mf) {
    #pragma unroll
    for (int nf = 0; nf < 2; ++nf) {
      const int hc = ft * 128 + wn * 32 + nf * 16 + ml;
      const float bias = dwnb[(size_t)e * H_DIM + hc];
      #pragma unroll
      for (int r = 0; r < 4; ++r) {
        const int m = tile * BM + wm * 64 + mf * 16 + lh * 4 + r;
        if (m < count) {
          const int slot = off + m;
          partial[(size_t)tmap[slot] * H_DIM + hc] =
              f2bf(wgrp[slot] * (acc[mf][nf][r] + bias));
        }
      }
    }
  }
}

// ---------------- 5. reduce bf16 partials over k ----------------
__global__ __launch_bounds__(256)
void reduce_kernel(const unsigned short* __restrict__ partial, float* __restrict__ out) {
  const int idx = blockIdx.x * 256 + threadIdx.x;   // T_TOK * 96 total
  const int t = idx / 96, g = idx - (idx / 96) * 96;
  const int h0 = g * 8;
  float s[8] = {0, 0, 0, 0, 0, 0, 0, 0};
  #pragma unroll
  for (int k = 0; k < 4; ++k) {
    const us8 p = *(const us8*)&partial[(size_t)(t * 4 + k) * H_DIM + h0];
    #pragma unroll
    for (int j = 0; j < 8; ++j)
      s[j] += __uint_as_float((unsigned)p[j] << 16);
  }
  f32x4 o0 = {s[0], s[1], s[2], s[3]};
  f32x4 o1 = {s[4], s[5], s[6], s[7]};
  *(f32x4*)&out[(size_t)t * H_DIM + h0] = o0;
  *(f32x4*)&out[(size_t)t * H_DIM + h0 + 4] = o1;
}

extern "C" void kernel_launch(void* const* d_in, const int* in_sizes, int n_in,
                              void* d_out, int out_size, void* d_ws, size_t ws_size,
                              hipStream_t stream) {
  const float* x    = (const float*)d_in[0];
  const float* rw   = (const float*)d_in[1];
  const float* rb   = (const float*)d_in[2];
  const float* gup  = (const float*)d_in[3];
  const float* gupb = (const float*)d_in[4];
  const float* dwn  = (const float*)d_in[5];
  const float* dwnb = (const float*)d_in[6];
  float* out = (float*)d_out;
  float* scores = out + (size_t)T_TOK * H_DIM;

  char* w = (char*)d_ws;
  int*   tk_idx = (int*)w;            w += NASSIGN * 4;
  float* tk_w   = (float*)w;          w += NASSIGN * 4;
  int*   counts = (int*)w;            w += 64;
  int*   offs   = (int*)w;            w += 64;
  int*   tmap   = (int*)w;            w += NSLOTP * 4;
  float* wgrp   = (float*)w;          w += NSLOTP * 4;
  unsigned short* gw = (unsigned short*)w; w += (size_t)E_NUM * KT * 12 * WTILE * 2;
  unsigned short* uw = (unsigned short*)w; w += (size_t)E_NUM * KT * 12 * WTILE * 2;
  unsigned short* dw = (unsigned short*)w; w += (size_t)E_NUM * KT * 12 * WTILE * 2;
  unsigned short* xg = (unsigned short*)w; w += (size_t)T_TOK * H_DIM * 2;
  unsigned short* act = (unsigned short*)w; w += (size_t)NTILE * KT * CHUNK * 2;
  unsigned short* partial = (unsigned short*)w; w += (size_t)NASSIGN * H_DIM * 2;

  router_kernel<<<NRTR, 256, 0, stream>>>(x, rw, rb, scores, tk_idx, tk_w, tmap, wgrp, xg);
  convert_w_kernel<<<dim3(192, 8, 2), 512, 0, stream>>>(
      gup, dwn, gw, uw, dw, tk_idx, tk_w, counts, offs, tmap, wgrp);
  gemm1_kernel<<<6 * E_NUM * MAXT1, 512, 0, stream>>>(
      xg, gw, uw, gupb, counts, offs, tmap, act);
  gemm2_kernel<<<6 * E_NUM * MAXT1, 512, 0, stream>>>(
      act, dw, dwnb, counts, offs, tmap, wgrp, partial);
  reduce_kernel<<<(T_TOK * 96) / 256, 256, 0, stream>>>(partial, out);
}

// Round 24
// 105.535 us; speedup vs baseline: 1.0199x; 1.0053x over previous
//
#include <hip/hip_runtime.h>
#include <hip/hip_bf16.h>

#define T_TOK 2048
#define H_DIM 768
#define E_NUM 16
#define F_DIM 768
#define TWOF 1536
#define TOPK 4
#define NASSIGN 8192
#define BM 128
#define BK 64
#define KT 12            /* 768/64 k-tiles */
#define NTILE 80         /* padded slots / BM = 10240/128 */
#define NSLOTP (NTILE * BM)
#define MAXT1 10         /* max tiles per expert (count <= 1280) */
#define CHUNK (BM * BK)  /* 8192 halfwords per A/act chunk */
#define WTILE (64 * BK)  /* 4096 halfwords per 64-col weight tile */
#define KSL 6144         /* halfwords per (e,kt,k8) slice: 12 ft x 512 */
#define NRTR 256         /* router blocks: 2048 / 8 */

typedef __bf16 bf16x8 __attribute__((ext_vector_type(8)));
typedef unsigned short us8 __attribute__((ext_vector_type(8)));
typedef float f32x4 __attribute__((ext_vector_type(4)));

__device__ __forceinline__ unsigned short f2bf(float f) {
  unsigned u = __float_as_uint(f);
  u += 0x7FFF + ((u >> 16) & 1);
  return (unsigned short)(u >> 16);
}

__device__ __forceinline__ void gl_lds16(const unsigned short* g, unsigned short* l) {
  __builtin_amdgcn_global_load_lds(
      (const __attribute__((address_space(1))) unsigned int*)g,
      (__attribute__((address_space(3))) unsigned int*)l, 16, 0, 0);
}

// ---------------- 1. router: LDS-free fp64 dot + token-order x->bf16 stream ----------------
__global__ __launch_bounds__(256)
void router_kernel(const float* __restrict__ x, const float* __restrict__ rw,
                   const float* __restrict__ rb, float* __restrict__ scores,
                   int* __restrict__ tk_idx, float* __restrict__ tk_w,
                   int* __restrict__ tmap, float* __restrict__ wgrp,
                   unsigned short* __restrict__ xg) {
  __shared__ float lg[8][16], sc[8][16];
  const int bid = blockIdx.x;
  const int tid = threadIdx.x;
  const int t0 = bid * 8;
  if (tid < 40) {  // 256 blocks x 40 = NSLOTP padded-slot init
    tmap[bid * 40 + tid] = 0;
    wgrp[bid * 40 + tid] = 0.0f;
  }
  { // stream-convert this block's 8 tokens to bf16 (token order, plain layout)
    const int tokr = tid >> 5;          // 0..7
    const int g0 = tid & 31;
    const float* xs = x + (size_t)(t0 + tokr) * H_DIM;
    unsigned short* xd = xg + (size_t)(t0 + tokr) * H_DIM;
    #pragma unroll
    for (int i = 0; i < 3; ++i) {
      const int gg = g0 + i * 32;       // 0..95 (8-halfword granules)
      const f32x4 a = *(const f32x4*)(xs + gg * 8);
      const f32x4 b = *(const f32x4*)(xs + gg * 8 + 4);
      us8 o;
      #pragma unroll
      for (int j = 0; j < 4; ++j) { o[j] = f2bf(a[j]); o[4 + j] = f2bf(b[j]); }
      *(us8*)&xd[gg * 8] = o;
    }
  }
  const int lane32 = tid & 31, tok = tid >> 5;
  const int e = lane32 & 15, q2 = lane32 >> 4;
  const int t = t0 + tok;
  const float* xr = x + (size_t)t * H_DIM + q2 * 384;
  const float* wr = rw + (size_t)e * H_DIM + q2 * 384;
  double a0 = 0, a1 = 0, a2 = 0, a3 = 0;
  #pragma unroll 4
  for (int h = 0; h < 384; h += 4) {
    const f32x4 xv = *(const f32x4*)(xr + h);
    const f32x4 wv = *(const f32x4*)(wr + h);
    a0 += (double)xv[0] * (double)wv[0];
    a1 += (double)xv[1] * (double)wv[1];
    a2 += (double)xv[2] * (double)wv[2];
    a3 += (double)xv[3] * (double)wv[3];
  }
  double acc = (a0 + a1) + (a2 + a3);
  acc += __shfl_xor(acc, 16, 64);   // combine the two h-halves
  if (q2 == 0) lg[tok][e] = (float)acc + rb[e];
  __syncthreads();
  if (lane32 == 0) {
    float v[16];
    #pragma unroll
    for (int i = 0; i < 16; ++i) { v[i] = lg[tok][i]; sc[tok][i] = 0.0f; }
    int idx[TOPK]; float val[TOPK];
    for (int k = 0; k < TOPK; ++k) {
      float best = -3.4e38f; int bi = 0;
      for (int i = 0; i < 16; ++i)
        if (v[i] > best) { best = v[i]; bi = i; }
      idx[k] = bi; val[k] = best; v[bi] = -3.4e38f;
    }
    float s = 0.0f, ev[TOPK];
    for (int k = 0; k < TOPK; ++k) { ev[k] = expf(val[k] - val[0]); s += ev[k]; }
    for (int k = 0; k < TOPK; ++k) {
      float wgt = ev[k] / s;
      sc[tok][idx[k]] = wgt;
      tk_idx[t * TOPK + k] = idx[k];
      tk_w[t * TOPK + k] = wgt;
    }
  }
  __syncthreads();
  if (tid < 128)
    scores[(size_t)(t0 + (tid >> 4)) * 16 + (tid & 15)] = sc[tid >> 4][tid & 15];
}

// ---------------- 2. weight convert v7: streaming reads + 12KB-contiguous writes (ft-major tiles) ----------------
// slice layout: element (n,k) of (e,kt,ft) tile at ((e*KT+kt)*8 + k8)*KSL + ft*512 + ((n^(k8&7))<<3) + (k&7)
__global__ __launch_bounds__(512)
void convert_w_kernel(const float* __restrict__ gup, const float* __restrict__ dwn,
                      unsigned short* __restrict__ gw, unsigned short* __restrict__ uw,
                      unsigned short* __restrict__ dw,
                      const int* __restrict__ tk_idx, const float* __restrict__ tk_w,
                      int* __restrict__ counts, int* __restrict__ offs,
                      int* __restrict__ tmap, float* __restrict__ wgrp) {
  const int xe = blockIdx.x;            // 0..191: e*12+kt
  const int e = xe / 12, kt = xe % 12;
  const int r8 = blockIdx.y;            // 0..7: k-octet
  const int z = blockIdx.z;             // 0: gate_up, 1: down
  const int tid = threadIdx.x;
  __shared__ unsigned short buf[12288]; // 24.6 KB; [row][f] bf16 staging; hist alias in group phase
  __shared__ int seg[16][16];
  __shared__ int cnt[16], eoff[16];
  const size_t slice = ((size_t)(e * KT + kt) * 8 + r8) * KSL;
  if (z == 0) {
    unsigned short* lg = buf;           // gate [8][768]
    unsigned short* lu = buf + 6144;    // up   [8][768]
    const float* src = gup + ((size_t)(e * H_DIM + kt * 64 + r8 * 8)) * TWOF;
    #pragma unroll
    for (int i = 0; i < 6; ++i) {
      const int q = i * 512 + tid;      // f32x4 index, 0..3071 (contiguous 48KB stream)
      const f32x4 v = *(const f32x4*)(src + 4 * q);
      const int row = q / 384;
      const int fp = (q - row * 384) * 2;   // f-col of first pair
      const int a = row * 768 + fp;
      *(unsigned*)&lg[a] = (unsigned)f2bf(v[0]) | ((unsigned)f2bf(v[2]) << 16);
      *(unsigned*)&lu[a] = (unsigned)f2bf(v[1]) | ((unsigned)f2bf(v[3]) << 16);
    }
    __syncthreads();
    #pragma unroll
    for (int i = 0; i < 3; ++i) {
      const int o = i * 512 + tid;      // 0..1535: which*768 + ft*64 + n
      const int which = o / 768;
      const int rem = o - which * 768;
      const int ft = rem >> 6, n = rem & 63;
      const unsigned short* ls = which ? lu : lg;
      us8 v;
      #pragma unroll
      for (int j = 0; j < 8; ++j) v[j] = ls[j * 768 + rem];
      unsigned short* dst = (which ? uw : gw)
          + slice + ft * 512 + ((n ^ (r8 & 7)) << 3);
      *(us8*)dst = v;
    }
  } else {
    unsigned short* lv = buf;           // [8][768]
    const float* src = dwn + ((size_t)(e * F_DIM + kt * 64 + r8 * 8)) * H_DIM;
    #pragma unroll
    for (int i = 0; i < 3; ++i) {
      const int q = i * 512 + tid;      // 0..1535 (contiguous 24KB stream)
      const f32x4 v = *(const f32x4*)(src + 4 * q);
      const int row = q / 192;
      const int c = (q - row * 192) * 4;
      const int a = row * 768 + c;
      *(unsigned*)&lv[a]     = (unsigned)f2bf(v[0]) | ((unsigned)f2bf(v[1]) << 16);
      *(unsigned*)&lv[a + 2] = (unsigned)f2bf(v[2]) | ((unsigned)f2bf(v[3]) << 16);
    }
    __syncthreads();
    for (int o = tid; o < 768; o += 512) {
      const int ft = o >> 6, n = o & 63;
      us8 v;
      #pragma unroll
      for (int j = 0; j < 8; ++j) v[j] = lv[j * 768 + o];
      unsigned short* dst = dw + slice + ft * 512 + ((n ^ (r8 & 7)) << 3);
      *(us8*)dst = v;
    }
  }
  // ---- deterministic group-by-expert, appended to block (0,0,0) ----
  if (xe == 0 && r8 == 0 && z == 0) {
    int (*hist)[16] = (int(*)[16])buf;   // 16 KB alias (convert phase done with buf)
    __syncthreads();
    int loc[16];
    int eid[32];
    if (tid < 256) {
      #pragma unroll
      for (int e2 = 0; e2 < 16; ++e2) loc[e2] = 0;
      const int base = tid * 32;
      for (int i = 0; i < 32; ++i) { int e2 = tk_idx[base + i]; eid[i] = e2; loc[e2]++; }
      #pragma unroll
      for (int e2 = 0; e2 < 16; ++e2) hist[tid][e2] = loc[e2];
    }
    __syncthreads();
    const int s = (tid >> 4) & 15, e16 = tid & 15;
    if (tid < 256) {
      int sum = 0;
      #pragma unroll
      for (int j = 0; j < 16; ++j) sum += hist[s * 16 + j][e16];
      seg[s][e16] = sum;
    }
    __syncthreads();
    if (tid < 16) {
      int run = 0;
      #pragma unroll
      for (int s2 = 0; s2 < 16; ++s2) { int t = seg[s2][tid]; seg[s2][tid] = run; run += t; }
      cnt[tid] = run;
    }
    __syncthreads();
    if (tid < 256) {
      int run = seg[s][e16];
      #pragma unroll
      for (int j = 0; j < 16; ++j) { int t = hist[s * 16 + j][e16]; hist[s * 16 + j][e16] = run; run += t; }
    }
    __syncthreads();
    if (tid == 0) {
      int acc = 0;
      for (int e2 = 0; e2 < 16; ++e2) { eoff[e2] = acc; acc += (cnt[e2] + BM - 1) / BM * BM; }
    }
    __syncthreads();
    if (tid < 16) { counts[tid] = cnt[tid]; offs[tid] = eoff[tid]; }
    if (tid < 256) {
      int run[16];
      #pragma unroll
      for (int e2 = 0; e2 < 16; ++e2) run[e2] = hist[tid][e2];
      const int base = tid * 32;
      for (int i = 0; i < 32; ++i) {
        int e2 = eid[i];
        int slot = eoff[e2] + run[e2]++;
        tmap[slot] = base + i;        // assignment id = t*4 + k
        wgrp[slot] = tk_w[base + i];
      }
    }
  }
}

// ---------------- 3. grouped GEMM1: A from token-order xg; B from ft-major k8 slices ----------------
__global__ __launch_bounds__(512)
void gemm1_kernel(const unsigned short* __restrict__ xg, const unsigned short* __restrict__ gw,
                  const unsigned short* __restrict__ uw, const float* __restrict__ gupb,
                  const int* __restrict__ counts, const int* __restrict__ offs,
                  const int* __restrict__ tmap, unsigned short* __restrict__ act) {
  // 960 blocks = 8 XCDs x 120; bijective
  const int bid = blockIdx.x;
  const int swz = (bid & 7) * 120 + (bid >> 3);
  const int ey = swz / 6, ft = swz % 6;
  const int e = ey / MAXT1, tile = ey % MAXT1;
  const int count = counts[e];
  if (tile * BM >= count) return;
  const int tileg = (offs[e] >> 7) + tile;
  const int tid = threadIdx.x;
  const int wv = tid >> 6, lane = tid & 63;
  const int ml = lane & 15, lh = lane >> 4;
  const int wm = wv >> 2, wn = wv & 3;

  __shared__ unsigned short lA[CHUNK];    // 16KB A tile [128][64], LDS-linear
  __shared__ unsigned short lBg[CHUNK];   // 16KB gate: [k8][2ft][perm-n]
  __shared__ unsigned short lBu[CHUNK];   // 16KB up

  const int arow = tid >> 3;
  const int agr = (tid & 7) ^ (arow & 7);   // (arow+64)&7 == arow&7
  const int t0 = tmap[tileg * BM + arow] >> 2;
  const int t1 = tmap[tileg * BM + 64 + arow] >> 2;
  const unsigned short* a0 = xg + (size_t)t0 * H_DIM + agr * 8;
  const unsigned short* a1 = xg + (size_t)t1 * H_DIM + agr * 8;

  // B staging granule offsets within a kt-slice-set: granule g -> (g>>7)*KSL + (g&127)*8
  const int bo0 = (tid >> 7) * KSL + (tid & 127) * 8;
  const int t2 = 512 + tid;
  const int bo1 = (t2 >> 7) * KSL + (t2 & 127) * 8;
  const unsigned short* gb = gw + (size_t)(e * KT) * 8 * KSL + ft * 2 * 512;
  const unsigned short* ub = uw + (size_t)(e * KT) * 8 * KSL + ft * 2 * 512;

  f32x4 accg[4][2] = {};
  f32x4 accu[4][2] = {};

  for (int kt = 0; kt < KT; ++kt) {
    const unsigned short* gs = gb + (size_t)kt * 8 * KSL;
    const unsigned short* us = ub + (size_t)kt * 8 * KSL;
    gl_lds16(a0 + kt * 64, &lA[tid * 8]);
    gl_lds16(a1 + kt * 64, &lA[(512 + tid) * 8]);
    gl_lds16(gs + bo0, &lBg[tid * 8]);
    gl_lds16(gs + bo1, &lBg[t2 * 8]);
    gl_lds16(us + bo0, &lBu[tid * 8]);
    gl_lds16(us + bo1, &lBu[t2 * 8]);
    __syncthreads();
    #pragma unroll
    for (int ks = 0; ks < 2; ++ks) {
      const int slot = ks * 4 + lh;
      bf16x8 af[4];
      #pragma unroll
      for (int mf = 0; mf < 4; ++mf) {
        const int ar = wm * 64 + mf * 16 + ml;
        af[mf] = __builtin_bit_cast(bf16x8, *(const us8*)&lA[ar * BK + 8 * (slot ^ (ar & 7))]);
      }
      #pragma unroll
      for (int nf = 0; nf < 2; ++nf) {
        const int br = wn * 32 + nf * 16 + ml;      // 0..127
        const int ba = slot * 1024 + (br >> 6) * 512 + (((br & 63) ^ (slot & 7)) << 3);
        bf16x8 bg = __builtin_bit_cast(bf16x8, *(const us8*)&lBg[ba]);
        bf16x8 bu = __builtin_bit_cast(bf16x8, *(const us8*)&lBu[ba]);
        #pragma unroll
        for (int mf = 0; mf < 4; ++mf) {
          accg[mf][nf] = __builtin_amdgcn_mfma_f32_16x16x32_bf16(af[mf], bg, accg[mf][nf], 0, 0, 0);
          accu[mf][nf] = __builtin_amdgcn_mfma_f32_16x16x32_bf16(af[mf], bu, accu[mf][nf], 0, 0, 0);
        }
      }
    }
    __syncthreads();
  }
  // epilogue: activation; chunk0 (cols 0..63) -> lA, chunk1 (cols 64..127) -> lBg (act layout unchanged)
  unsigned short* tbuf = (wn & 2) ? lBg : lA;
  #pragma unroll
  for (int mf = 0; mf < 4; ++mf) {
    #pragma unroll
    for (int nf = 0; nf < 2; ++nf) {
      const int fcl = wn * 32 + nf * 16 + ml;       // 0..127
      const int c = fcl & 63;
      const int fc = ft * 128 + fcl;
      const float bgv = gupb[(size_t)e * TWOF + 2 * fc];
      const float buv = gupb[(size_t)e * TWOF + 2 * fc + 1];
      #pragma unroll
      for (int r = 0; r < 4; ++r) {
        const int m = wm * 64 + mf * 16 + lh * 4 + r;
        float g = accg[mf][nf][r] + bgv;
        float u = accu[mf][nf][r] + buv;
        g = fminf(g, 7.0f);
        u = fminf(fmaxf(u, -7.0f), 7.0f);
        const float glu = g / (1.0f + __expf(-1.702f * g));
        tbuf[m * BK + 8 * ((c >> 3) ^ (m & 7)) + (c & 7)] = f2bf((u + 1.0f) * glu);
      }
    }
  }
  __syncthreads();
  unsigned short* ob0 = act + ((size_t)tileg * KT + ft * 2) * CHUNK;
  unsigned short* ob1 = ob0 + CHUNK;
  #pragma unroll
  for (int i = 0; i < 2; ++i) {
    *(us8*)&ob0[(i * 512 + tid) * 8] = *(const us8*)&lA[(i * 512 + tid) * 8];
    *(us8*)&ob1[(i * 512 + tid) * 8] = *(const us8*)&lBg[(i * 512 + tid) * 8];
  }
}

// ---------------- 4. grouped GEMM2: A = act (old layout), B = dw (ft-major k8 slices), bf16 partial ----------------
__global__ __launch_bounds__(512)
void gemm2_kernel(const unsigned short* __restrict__ act, const unsigned short* __restrict__ dw,
                  const float* __restrict__ dwnb, const int* __restrict__ counts,
                  const int* __restrict__ offs, const int* __restrict__ tmap,
                  const float* __restrict__ wgrp, unsigned short* __restrict__ partial) {
  const int bid = blockIdx.x;
  const int swz = (bid & 7) * 120 + (bid >> 3);
  const int ey = swz / 6, ft = swz % 6;
  const int e = ey / MAXT1, tile = ey % MAXT1;
  const int count = counts[e];
  if (tile * BM >= count) return;
  const int off = offs[e];
  const int tileg = (off >> 7) + tile;
  const int tid = threadIdx.x;
  const int wv = tid >> 6, lane = tid & 63;
  const int ml = lane & 15, lh = lane >> 4;
  const int wm = wv >> 2, wn = wv & 3;

  __shared__ unsigned short lA[CHUNK];   // 16KB
  __shared__ unsigned short lB[CHUNK];   // 16KB: [k8][2ft][perm-n]

  const unsigned short* ab = act + (size_t)tileg * KT * CHUNK;
  const int bo0 = (tid >> 7) * KSL + (tid & 127) * 8;
  const int t2 = 512 + tid;
  const int bo1 = (t2 >> 7) * KSL + (t2 & 127) * 8;
  const unsigned short* bb = dw + (size_t)(e * KT) * 8 * KSL + ft * 2 * 512;

  f32x4 acc[4][2] = {};

  for (int kt = 0; kt < KT; ++kt) {
    const unsigned short* as = ab + kt * CHUNK;
    const unsigned short* bs = bb + (size_t)kt * 8 * KSL;
    gl_lds16(as + tid * 8, &lA[tid * 8]);
    gl_lds16(as + (512 + tid) * 8, &lA[(512 + tid) * 8]);
    gl_lds16(bs + bo0, &lB[tid * 8]);
    gl_lds16(bs + bo1, &lB[t2 * 8]);
    __syncthreads();
    #pragma unroll
    for (int ks = 0; ks < 2; ++ks) {
      const int slot = ks * 4 + lh;
      bf16x8 af[4];
      #pragma unroll
      for (int mf = 0; mf < 4; ++mf) {
        const int ar = wm * 64 + mf * 16 + ml;
        af[mf] = __builtin_bit_cast(bf16x8, *(const us8*)&lA[ar * BK + 8 * (slot ^ (ar & 7))]);
      }
      #pragma unroll
      for (int nf = 0; nf < 2; ++nf) {
        const int br = wn * 32 + nf * 16 + ml;
        const int ba = slot * 1024 + (br >> 6) * 512 + (((br & 63) ^ (slot & 7)) << 3);
        bf16x8 bv = __builtin_bit_cast(bf16x8, *(const us8*)&lB[ba]);
        #pragma unroll
        for (int mf = 0; mf < 4; ++mf)
          acc[mf][nf] = __builtin_amdgcn_mfma_f32_16x16x32_bf16(af[mf], bv, acc[mf][nf], 0, 0, 0);
      }
    }
    __syncthreads();
  }
  #pragma unroll
  for (int mf = 0; mf < 4; ++mf) {
    #pragma unroll
    for (int nf = 0; nf < 2; ++nf) {
      const int hc = ft * 128 + wn * 32 + nf * 16 + ml;
      const float bias = dwnb[(size_t)e * H_DIM + hc];
      #pragma unroll
      for (int r = 0; r < 4; ++r) {
        const int m = tile * BM + wm * 64 + mf * 16 + lh * 4 + r;
        if (m < count) {
          const int slot = off + m;
          partial[(size_t)tmap[slot] * H_DIM + hc] =
              f2bf(wgrp[slot] * (acc[mf][nf][r] + bias));
        }
      }
    }
  }
}

// ---------------- 5. reduce bf16 partials over k ----------------
__global__ __launch_bounds__(256)
void reduce_kernel(const unsigned short* __restrict__ partial, float* __restrict__ out) {
  const int idx = blockIdx.x * 256 + threadIdx.x;   // T_TOK * 96 total
  const int t = idx / 96, g = idx - (idx / 96) * 96;
  const int h0 = g * 8;
  float s[8] = {0, 0, 0, 0, 0, 0, 0, 0};
  #pragma unroll
  for (int k = 0; k < 4; ++k) {
    const us8 p = *(const us8*)&partial[(size_t)(t * 4 + k) * H_DIM + h0];
    #pragma unroll
    for (int j = 0; j < 8; ++j)
      s[j] += __uint_as_float((unsigned)p[j] << 16);
  }
  f32x4 o0 = {s[0], s[1], s[2], s[3]};
  f32x4 o1 = {s[4], s[5], s[6], s[7]};
  *(f32x4*)&out[(size_t)t * H_DIM + h0] = o0;
  *(f32x4*)&out[(size_t)t * H_DIM + h0 + 4] = o1;
}

extern "C" void kernel_launch(void* const* d_in, const int* in_sizes, int n_in,
                              void* d_out, int out_size, void* d_ws, size_t ws_size,
                              hipStream_t stream) {
  const float* x    = (const float*)d_in[0];
  const float* rw   = (const float*)d_in[1];
  const float* rb   = (const float*)d_in[2];
  const float* gup  = (const float*)d_in[3];
  const float* gupb = (const float*)d_in[4];
  const float* dwn  = (const float*)d_in[5];
  const float* dwnb = (const float*)d_in[6];
  float* out = (float*)d_out;
  float* scores = out + (size_t)T_TOK * H_DIM;

  char* w = (char*)d_ws;
  int*   tk_idx = (int*)w;            w += NASSIGN * 4;
  float* tk_w   = (float*)w;          w += NASSIGN * 4;
  int*   counts = (int*)w;            w += 64;
  int*   offs   = (int*)w;            w += 64;
  int*   tmap   = (int*)w;            w += NSLOTP * 4;
  float* wgrp   = (float*)w;          w += NSLOTP * 4;
  unsigned short* gw = (unsigned short*)w; w += (size_t)E_NUM * KT * 8 * KSL * 2;
  unsigned short* uw = (unsigned short*)w; w += (size_t)E_NUM * KT * 8 * KSL * 2;
  unsigned short* dw = (unsigned short*)w; w += (size_t)E_NUM * KT * 8 * KSL * 2;
  unsigned short* xg = (unsigned short*)w; w += (size_t)T_TOK * H_DIM * 2;
  unsigned short* act = (unsigned short*)w; w += (size_t)NTILE * KT * CHUNK * 2;
  unsigned short* partial = (unsigned short*)w; w += (size_t)NASSIGN * H_DIM * 2;

  router_kernel<<<NRTR, 256, 0, stream>>>(x, rw, rb, scores, tk_idx, tk_w, tmap, wgrp, xg);
  convert_w_kernel<<<dim3(192, 8, 2), 512, 0, stream>>>(
      gup, dwn, gw, uw, dw, tk_idx, tk_w, counts, offs, tmap, wgrp);
  gemm1_kernel<<<6 * E_NUM * MAXT1, 512, 0, stream>>>(
      xg, gw, uw, gupb, counts, offs, tmap, act);
  gemm2_kernel<<<6 * E_NUM * MAXT1, 512, 0, stream>>>(
      act, dw, dwnb, counts, offs, tmap, wgrp, partial);
  reduce_kernel<<<(T_TOK * 96) / 256, 256, 0, stream>>>(partial, out);
}